// Round 5
// baseline (336.226 us; speedup 1.0000x reference)
//
#include <hip/hip_runtime.h>
#include <stdint.h>
#include <stddef.h>

typedef unsigned short u16;
typedef unsigned int u32;
typedef __attribute__((ext_vector_type(8))) __bf16 bf16x8;
typedef __attribute__((ext_vector_type(4))) float f32x4;
typedef __attribute__((ext_vector_type(16))) float f32x16;

#define DEV __device__ __forceinline__

// ---- problem dims (hardcoded per reference) ----
#define BATCH 2
#define SEQ   2048
#define CDIM  1024
#define NH    16
#define KD    64
#define MROWS (BATCH * SEQ)   // 4096
#define NX (MROWS * CDIM)     // 4194304
#define NW (CDIM * CDIM)      // 1048576

DEV u16 f32_to_bf16(float f) {
  union { float f; unsigned u; } v; v.f = f;
  return (u16)((v.u + 0x7fffu + ((v.u >> 16) & 1u)) >> 16);
}
DEV float bf16_to_f32(u16 h) {
  union { unsigned u; float f; } v; v.u = ((unsigned)h) << 16;
  return v.f;
}
DEV u32 pack_bf16x2(float a, float b) {
  union { __bf16 h[2]; u32 u; } r;
  r.h[0] = (__bf16)a; r.h[1] = (__bf16)b;
  return r.u;
}
// truncation pack: low16 = hi16(a), high16 = hi16(b) -- single v_perm_b32
DEV u32 pack_trunc(float a, float b) {
  return __builtin_amdgcn_perm(__float_as_uint(b), __float_as_uint(a), 0x07060302u);
}

// async global->LDS, 16B per lane
DEV void gl_lds16(const u16* g, u16* l) {
  __builtin_amdgcn_global_load_lds(
      (const __attribute__((address_space(1))) void*)(g),
      (__attribute__((address_space(3))) void*)(l), 16, 0, 0);
}

// ---------------- fused f32 -> bf16 convert (x, W_proj, W_mix) ----------------
__global__ void cvt_all(const float* __restrict__ x, const float* __restrict__ wp,
                        const float* __restrict__ wm,
                        u16* __restrict__ xb, u16* __restrict__ wpb, u16* __restrict__ wmb) {
  int total4 = (NX + 2 * NW) >> 2;
  for (int i4 = blockIdx.x * blockDim.x + threadIdx.x; i4 < total4;
       i4 += gridDim.x * blockDim.x) {
    int i = i4 << 2;
    const float* src; u16* dst; int off;
    if (i < NX)           { src = x;  dst = xb;  off = i; }
    else if (i < NX + NW) { src = wp; dst = wpb; off = i - NX; }
    else                  { src = wm; dst = wmb; off = i - NX - NW; }
    float4 v = *reinterpret_cast<const float4*>(src + off);
    ushort4 o;
    o.x = f32_to_bf16(v.x); o.y = f32_to_bf16(v.y);
    o.z = f32_to_bf16(v.z); o.w = f32_to_bf16(v.w);
    *reinterpret_cast<ushort4*>(dst + off) = o;
  }
}

// ---------------- metric = (row-softmax of tril(pm)/8) @ P^T ----------------
__global__ void metric_kernel(const float* __restrict__ pm, float* __restrict__ metric) {
  int h = blockIdx.x, t = threadIdx.x;
  __shared__ float P[64][65];
  if (t < 64) {
    int i = t;
    const float* row = pm + (size_t)(h * 64 + i) * 64;
    float mx = -1e30f;
    for (int j = 0; j <= i; ++j) mx = fmaxf(mx, row[j] * 0.125f);
    float s = 0.f;
    for (int j = 0; j <= i; ++j) { float e = expf(row[j] * 0.125f - mx); P[i][j] = e; s += e; }
    float inv = 1.f / s;
    for (int j = 0; j <= i; ++j) P[i][j] *= inv;
    for (int j = i + 1; j < 64; ++j) P[i][j] = 0.f;
  }
  __syncthreads();
  int i = t >> 2;
  int jb = (t & 3) * 16;
  for (int jj = 0; jj < 16; ++jj) {
    int j = jb + jj;
    float acc = 0.f;
    #pragma unroll
    for (int l = 0; l < 64; ++l) acc += P[i][l] * P[j][l];
    metric[(size_t)h * 4096 + i * 64 + j] = acc;
  }
}

// ---------------- bf16 MFMA GEMM: C = A @ B^T, global_load_lds staging ----------------
template <int MODE>
__launch_bounds__(256)
__global__ void gemm_xwt(const u16* __restrict__ A, const u16* __restrict__ B,
                         void* __restrict__ C0, int M, int N, int K) {
  __shared__ __align__(16) u16 As[128 * 32];
  __shared__ __align__(16) u16 Bs[128 * 32];
  int bm0 = blockIdx.y * 128, bn0 = blockIdx.x * 128;
  int t = threadIdx.x, wv = t >> 6, lane = t & 63;
  int wr = wv >> 1, wc = wv & 1;
  int l15 = lane & 15, l4 = lane >> 4;
  int rl = lane >> 2, cseg = (lane & 3) * 8;
  f32x4 acc[4][4] = {};

  for (int k0 = 0; k0 < K; k0 += 32) {
    #pragma unroll
    for (int q = 0; q < 2; ++q) {
      int rbase = (wv * 2 + q) * 16;
      gl_lds16(A + (size_t)(bm0 + rbase + rl) * K + k0 + cseg, As + rbase * 32);
      gl_lds16(B + (size_t)(bn0 + rbase + rl) * K + k0 + cseg, Bs + rbase * 32);
    }
    __syncthreads();
    bf16x8 af[4], bfm[4];
    #pragma unroll
    for (int m = 0; m < 4; ++m)
      af[m] = *reinterpret_cast<const bf16x8*>(As + (wr * 64 + m * 16 + l15) * 32 + l4 * 8);
    #pragma unroll
    for (int nn = 0; nn < 4; ++nn)
      bfm[nn] = *reinterpret_cast<const bf16x8*>(Bs + (wc * 64 + nn * 16 + l15) * 32 + l4 * 8);
    #pragma unroll
    for (int m = 0; m < 4; ++m)
      #pragma unroll
      for (int nn = 0; nn < 4; ++nn)
        acc[m][nn] = __builtin_amdgcn_mfma_f32_16x16x32_bf16(af[m], bfm[nn], acc[m][nn], 0, 0, 0);
    __syncthreads();
  }

  #pragma unroll
  for (int m = 0; m < 4; ++m) {
    int rbase = bm0 + wr * 64 + m * 16 + l4 * 4;
    #pragma unroll
    for (int nn = 0; nn < 4; ++nn) {
      int col = bn0 + wc * 64 + nn * 16 + l15;
      #pragma unroll
      for (int rr = 0; rr < 4; ++rr) {
        int row = rbase + rr;
        float v = acc[m][nn][rr];
        if (MODE == 0) {
          int bb = row >> 11, ww = row & 2047;
          int hh = col >> 6, kk = col & 63;
          ((u16*)C0)[(((size_t)(bb * NH + hh)) * SEQ + ww) * KD + kk] = f32_to_bf16(v);
        } else {
          ((float*)C0)[(size_t)row * N + col] = v;
        }
      }
    }
  }
}

// ---------------- qm = proj @ metric (per head); also emits projT [bh][d][w] ------
__launch_bounds__(256)
__global__ void qm_kernel(const u16* __restrict__ proj, const float* __restrict__ metric,
                          u16* __restrict__ qm, u16* __restrict__ projT) {
  int w0 = blockIdx.x * 32;
  int h = blockIdx.y, bb = blockIdx.z;
  __shared__ float M[64][65];
  __shared__ float Pr[32][64];
  int t = threadIdx.x;
  for (int i = t; i < 4096; i += 256) M[i >> 6][i & 63] = metric[(size_t)h * 4096 + i];
  const size_t bh = (size_t)bb * NH + h;
  const u16* pp = proj + (bh * SEQ + w0) * KD;
  for (int i = t; i < 2048; i += 256) Pr[i >> 6][i & 63] = bf16_to_f32(pp[i]);
  __syncthreads();
  int kk = t & 63, g = t >> 6;
  #pragma unroll
  for (int r8 = 0; r8 < 8; ++r8) {
    int r = r8 * 4 + g;
    float acc = 0.f;
    #pragma unroll
    for (int l = 0; l < 64; ++l) acc += Pr[r][l] * M[kk][l];  // M symmetric
    qm[(bh * SEQ + w0 + r) * KD + kk] = f32_to_bf16(acc);
  }
  // emit transposed V: projT[bh][d][w0 + ws8*8 .. +8]
  {
    int d = t & 63, ws8 = t >> 6;
    u16 tmp[8];
    #pragma unroll
    for (int i2 = 0; i2 < 8; ++i2) tmp[i2] = f32_to_bf16(Pr[ws8 * 8 + i2][d]);
    uint4 ov;
    ov.x = (u32)tmp[0] | ((u32)tmp[1] << 16);
    ov.y = (u32)tmp[2] | ((u32)tmp[3] << 16);
    ov.z = (u32)tmp[4] | ((u32)tmp[5] << 16);
    ov.w = (u32)tmp[6] | ((u32)tmp[7] << 16);
    *reinterpret_cast<uint4*>(projT + (bh * KD + d) * SEQ + w0 + ws8 * 8) = ov;
  }
}

// ---------------- causal flash attention: split-kv warps + LDS merge ----------------
// grid (32 bh, 32 pair), 256 threads = 4 warps.
// Block owns chunk pair (p, 63-p) -> uniform ~34 kv-tiles per block.
// Warps (2c+half): chunk = c? 63-p : p; half 0 takes kv tiles [0,hA), half 1 [hA,nt).
// Partials merged via LDS (O^T [64][33] f32 + m,l per chunk).
__launch_bounds__(256, 4)
__global__ void attn_kernel(const u16* __restrict__ qm, const u16* __restrict__ proj,
                            const u16* __restrict__ projT, u16* __restrict__ nudged) {
  const int bh = blockIdx.x;
  const int bb = bh >> 4, h = bh & 15;
  const int p = blockIdx.y;
  const int t = threadIdx.x, wv = t >> 6, lane = t & 63;
  const int c = lane & 31, hi = lane >> 5;
  const int cidx = wv >> 1, half = wv & 1;
  const int chunk = cidx ? (63 - p) : p;
  const int q0 = chunk * 32;
  const int q_row = q0 + c;

  __shared__ float smf[2][2176];   // per chunk: O^T[64][33] + m[32]@2112 + l[32]@2144

  const size_t bho = (size_t)bh * SEQ * KD;
  const u16* kp  = proj + bho;
  const u16* qmp = qm + bho;
  const u16* vtp = projT + bho;

  const int nt = (q0 + 95) >> 6;
  const int hA = nt >> 1;
  const int s0i = half ? hA : 0;
  const int cnt = half ? (nt - hA) : hA;

  // Q fragments (B-operand), held for the whole loop
  bf16x8 qf[4];
  #pragma unroll
  for (int kc = 0; kc < 4; ++kc)
    qf[kc] = *reinterpret_cast<const bf16x8*>(qmp + (size_t)q_row * KD + kc * 16 + hi * 8);

  f32x16 o0 = {}, o1 = {};
  float mrow = -1e30f, lrow = 0.f;
  const float cl2 = 0.125f * 1.44269504088896f;   // 1/sqrt(64) * log2(e)

  // per-lane running pointers (offsets fold to immediates)
  const u16* k0p = kp + ((size_t)s0i * 64 + c) * KD;
  const u16* k1p = k0p + 32 * KD;
  const u16* v0p = vtp + (size_t)c * SEQ + s0i * 64;
  const u16* v1p = v0p + 32 * SEQ;

  bf16x8 kf0[4], kf1[4], vf0[4], vf1[4];
  #pragma unroll
  for (int kc = 0; kc < 4; ++kc) {
    kf0[kc] = *reinterpret_cast<const bf16x8*>(k0p + kc * 16 + hi * 8);
    kf1[kc] = *reinterpret_cast<const bf16x8*>(k1p + kc * 16 + hi * 8);
    vf0[kc] = *reinterpret_cast<const bf16x8*>(v0p + kc * 16 + hi * 8);
    vf1[kc] = *reinterpret_cast<const bf16x8*>(v1p + kc * 16 + hi * 8);
  }
  k0p += 64 * KD; k1p += 64 * KD; v0p += 64; v1p += 64;

  for (int i = 0; i < cnt; ++i) {
    const int j0 = (s0i + i) * 64;
    // S^T = K @ qm^T : rows=kv, cols=q (lane c owns q-col c)
    f32x16 s0 = {}, s1 = {};
    #pragma unroll
    for (int kc = 0; kc < 4; ++kc) {
      s0 = __builtin_amdgcn_mfma_f32_32x32x16_bf16(kf0[kc], qf[kc], s0, 0, 0, 0);
      s1 = __builtin_amdgcn_mfma_f32_32x32x16_bf16(kf1[kc], qf[kc], s1, 0, 0, 0);
    }
    // prefetch next K tile (hidden under softmax + PV)
    if (i + 1 < cnt) {
      #pragma unroll
      for (int kc = 0; kc < 4; ++kc) {
        kf0[kc] = *reinterpret_cast<const bf16x8*>(k0p + kc * 16 + hi * 8);
        kf1[kc] = *reinterpret_cast<const bf16x8*>(k1p + kc * 16 + hi * 8);
      }
      k0p += 64 * KD; k1p += 64 * KD;
    }
    // causal mask (uniform branch; true only on diagonal-overlapping tiles)
    if (j0 + 63 > q0) {
      #pragma unroll
      for (int r = 0; r < 16; ++r) {
        int kvl = (r & 3) + 8 * (r >> 2) + 4 * hi;
        if (j0 + kvl      > q_row) s0[r] = -1e30f;
        if (j0 + 32 + kvl > q_row) s1[r] = -1e30f;
      }
    }
    // row max: tree + one cross-half swap
    float mx[16];
    #pragma unroll
    for (int r = 0; r < 16; ++r) mx[r] = fmaxf(s0[r], s1[r]);
    #pragma unroll
    for (int st = 8; st >= 1; st >>= 1)
      #pragma unroll
      for (int r = 0; r < st; ++r) mx[r] = fmaxf(mx[r], mx[r + st]);
    float pmax = fmaxf(mx[0], __shfl_xor(mx[0], 32));
    // T13 defer-max
    if (__any(pmax - mrow > 32.f)) {
      float mn = fmaxf(mrow, pmax);
      float alpha = exp2f((mrow - mn) * cl2);
      #pragma unroll
      for (int r = 0; r < 16; ++r) { o0[r] *= alpha; o1[r] *= alpha; }
      lrow *= alpha;
      mrow = mn;
    }
    const float mc = mrow * cl2;
    float sv[16];
    #pragma unroll
    for (int r = 0; r < 16; ++r) {
      float p0 = exp2f(s0[r] * cl2 - mc); s0[r] = p0;
      float p1 = exp2f(s1[r] * cl2 - mc); s1[r] = p1;
      sv[r] = p0 + p1;
    }
    #pragma unroll
    for (int st = 8; st >= 1; st >>= 1)
      #pragma unroll
      for (int r = 0; r < st; ++r) sv[r] += sv[r + st];
    lrow += sv[0] + __shfl_xor(sv[0], 32);

    // pack P to bf16 (truncation, 1 v_perm per pair)
    u32 w[2][4][2];
    #pragma unroll
    for (int q4 = 0; q4 < 4; ++q4) {
      w[0][q4][0] = pack_trunc(s0[q4 * 4 + 0], s0[q4 * 4 + 1]);
      w[0][q4][1] = pack_trunc(s0[q4 * 4 + 2], s0[q4 * 4 + 3]);
      w[1][q4][0] = pack_trunc(s1[q4 * 4 + 0], s1[q4 * 4 + 1]);
      w[1][q4][1] = pack_trunc(s1[q4 * 4 + 2], s1[q4 * 4 + 3]);
    }
    // exchange halves -> PA frags pa[ks] = P[q=q0+c][16ks+8hi+0..7]
    bf16x8 pa[4];
    #pragma unroll
    for (int tt = 0; tt < 2; ++tt) {
      #pragma unroll
      for (int j = 0; j < 2; ++j) {
        int own = 2 * j + hi, send = 2 * j + (hi ^ 1);
        u32 ra = __shfl_xor(w[tt][send][0], 32);
        u32 rb = __shfl_xor(w[tt][send][1], 32);
        union { u32 u[4]; bf16x8 v; } pk;
        if (hi == 0) { pk.u[0] = w[tt][own][0]; pk.u[1] = w[tt][own][1]; pk.u[2] = ra; pk.u[3] = rb; }
        else         { pk.u[0] = ra; pk.u[1] = rb; pk.u[2] = w[tt][own][0]; pk.u[3] = w[tt][own][1]; }
        pa[tt * 2 + j] = pk.v;
      }
    }
    // O^T += V^T @ P^T (stats stay lane-local)
    #pragma unroll
    for (int ks = 0; ks < 4; ++ks) {
      o0 = __builtin_amdgcn_mfma_f32_32x32x16_bf16(vf0[ks], pa[ks], o0, 0, 0, 0);
      o1 = __builtin_amdgcn_mfma_f32_32x32x16_bf16(vf1[ks], pa[ks], o1, 0, 0, 0);
    }
    // prefetch next V^T tile
    if (i + 1 < cnt) {
      #pragma unroll
      for (int ks = 0; ks < 4; ++ks) {
        vf0[ks] = *reinterpret_cast<const bf16x8*>(v0p + ks * 16 + hi * 8);
        vf1[ks] = *reinterpret_cast<const bf16x8*>(v1p + ks * 16 + hi * 8);
      }
      v0p += 64; v1p += 64;
    }
  }

  // ---- merge halves: odd warp publishes partials, even warp merges + stores ----
  float* Ob = smf[cidx];
  if (half == 1) {
    #pragma unroll
    for (int r = 0; r < 16; ++r) {
      int d = (r & 3) + 8 * (r >> 2) + 4 * hi;
      Ob[d * 33 + c] = o0[r];
      Ob[(d + 32) * 33 + c] = o1[r];
    }
    if (hi == 0) { Ob[2112 + c] = mrow; Ob[2144 + c] = lrow; }
  }
  __syncthreads();
  if (half == 0) {
    float mB = Ob[2112 + c], lB = Ob[2144 + c];
    float Mx = fmaxf(mrow, mB);
    float scA = exp2f((mrow - Mx) * cl2);
    float scB = exp2f((mB - Mx) * cl2);
    float invd = 1.f / (lrow * scA + lB * scB);
    float v0[16], v1[16];
    #pragma unroll
    for (int r = 0; r < 16; ++r) {
      int d = (r & 3) + 8 * (r >> 2) + 4 * hi;
      v0[r] = (o0[r] * scA + Ob[d * 33 + c] * scB) * invd;
      v1[r] = (o1[r] * scA + Ob[(d + 32) * 33 + c] * scB) * invd;
    }
    u16* orow = nudged + ((size_t)bb * SEQ + q_row) * CDIM + h * KD;
    #pragma unroll
    for (int g = 0; g < 4; ++g) {
      int d0 = g * 8 + hi * 4;
      uint2 a, b2;
      a.x  = pack_bf16x2(v0[g * 4 + 0], v0[g * 4 + 1]);
      a.y  = pack_bf16x2(v0[g * 4 + 2], v0[g * 4 + 3]);
      b2.x = pack_bf16x2(v1[g * 4 + 0], v1[g * 4 + 1]);
      b2.y = pack_bf16x2(v1[g * 4 + 2], v1[g * 4 + 3]);
      *reinterpret_cast<uint2*>(orow + d0)      = a;
      *reinterpret_cast<uint2*>(orow + 32 + d0) = b2;
    }
  }
}

// ---------------- host launch ----------------
extern "C" void kernel_launch(void* const* d_in, const int* in_sizes, int n_in,
                              void* d_out, int out_size, void* d_ws, size_t ws_size,
                              hipStream_t stream) {
  (void)in_sizes; (void)n_in; (void)out_size; (void)ws_size;
  const float* x      = (const float*)d_in[0];
  const float* Wproj  = (const float*)d_in[1];
  const float* premet = (const float*)d_in[2];
  const float* Wmix   = (const float*)d_in[3];

  char* w = (char*)d_ws;
  u16* x_bf   = (u16*)w;  w += (size_t)MROWS * CDIM * 2;        // 8 MB
  u16* wp_bf  = (u16*)w;  w += (size_t)CDIM * CDIM * 2;         // 2 MB
  u16* wm_bf  = (u16*)w;  w += (size_t)CDIM * CDIM * 2;         // 2 MB
  float* metric = (float*)w; w += (size_t)NH * KD * KD * 4;     // 256 KB
  u16* proj_bnwk = (u16*)w; w += (size_t)BATCH * NH * SEQ * KD * 2;  // 8 MB
  u16* projT     = (u16*)w; w += (size_t)BATCH * NH * KD * SEQ * 2;  // 8 MB
  u16* qm        = (u16*)w; w += (size_t)BATCH * NH * SEQ * KD * 2;  // 8 MB
  u16* nudged    = (u16*)w; w += (size_t)MROWS * CDIM * 2;           // 8 MB

  hipLaunchKernelGGL(cvt_all, dim3(2048), dim3(256), 0, stream,
                     x, Wproj, Wmix, x_bf, wp_bf, wm_bf);
  hipLaunchKernelGGL(metric_kernel, dim3(NH), dim3(256), 0, stream, premet, metric);
  hipLaunchKernelGGL((gemm_xwt<0>), dim3(CDIM / 128, MROWS / 128), dim3(256), 0, stream,
                     x_bf, wp_bf, (void*)proj_bnwk, MROWS, CDIM, CDIM);
  hipLaunchKernelGGL(qm_kernel, dim3(SEQ / 32, NH, BATCH), dim3(256), 0, stream,
                     proj_bnwk, metric, qm, projT);
  hipLaunchKernelGGL(attn_kernel, dim3(32, 32), dim3(256), 0, stream,
                     qm, proj_bnwk, projT, nudged);
  hipLaunchKernelGGL((gemm_xwt<1>), dim3(CDIM / 128, MROWS / 128), dim3(256), 0, stream,
                     nudged, wm_bf, d_out, MROWS, CDIM, CDIM);
}

// Round 6
// 224.886 us; speedup vs baseline: 1.4951x; 1.4951x over previous
//
#include <hip/hip_runtime.h>
#include <stdint.h>
#include <stddef.h>

typedef unsigned short u16;
typedef unsigned int u32;
typedef __attribute__((ext_vector_type(8))) __bf16 bf16x8;
typedef __attribute__((ext_vector_type(4))) float f32x4;
typedef __attribute__((ext_vector_type(16))) float f32x16;

#define DEV __device__ __forceinline__

// ---- problem dims (hardcoded per reference) ----
#define BATCH 2
#define SEQ   2048
#define CDIM  1024
#define NH    16
#define KD    64
#define MROWS (BATCH * SEQ)   // 4096
#define NX (MROWS * CDIM)     // 4194304
#define NW (CDIM * CDIM)      // 1048576

DEV u16 f32_to_bf16(float f) {
  union { float f; unsigned u; } v; v.f = f;
  return (u16)((v.u + 0x7fffu + ((v.u >> 16) & 1u)) >> 16);
}
DEV float bf16_to_f32(u16 h) {
  union { unsigned u; float f; } v; v.u = ((unsigned)h) << 16;
  return v.f;
}
DEV u32 pack_bf16x2(float a, float b) {
  union { __bf16 h[2]; u32 u; } r;
  r.h[0] = (__bf16)a; r.h[1] = (__bf16)b;
  return r.u;
}
// truncation pack: low16 = hi16(a), high16 = hi16(b) -- single v_perm_b32
DEV u32 pack_trunc(float a, float b) {
  return __builtin_amdgcn_perm(__float_as_uint(b), __float_as_uint(a), 0x07060302u);
}

// async global->LDS, 16B per lane
DEV void gl_lds16(const u16* g, u16* l) {
  __builtin_amdgcn_global_load_lds(
      (const __attribute__((address_space(1))) void*)(g),
      (__attribute__((address_space(3))) void*)(l), 16, 0, 0);
}

// ---------------- fused f32 -> bf16 convert (x, W_proj, W_mix) ----------------
__global__ void cvt_all(const float* __restrict__ x, const float* __restrict__ wp,
                        const float* __restrict__ wm,
                        u16* __restrict__ xb, u16* __restrict__ wpb, u16* __restrict__ wmb) {
  int total4 = (NX + 2 * NW) >> 2;
  for (int i4 = blockIdx.x * blockDim.x + threadIdx.x; i4 < total4;
       i4 += gridDim.x * blockDim.x) {
    int i = i4 << 2;
    const float* src; u16* dst; int off;
    if (i < NX)           { src = x;  dst = xb;  off = i; }
    else if (i < NX + NW) { src = wp; dst = wpb; off = i - NX; }
    else                  { src = wm; dst = wmb; off = i - NX - NW; }
    float4 v = *reinterpret_cast<const float4*>(src + off);
    ushort4 o;
    o.x = f32_to_bf16(v.x); o.y = f32_to_bf16(v.y);
    o.z = f32_to_bf16(v.z); o.w = f32_to_bf16(v.w);
    *reinterpret_cast<ushort4*>(dst + off) = o;
  }
}

// ---------------- metric = (row-softmax of tril(pm)/8) @ P^T ----------------
__global__ void metric_kernel(const float* __restrict__ pm, float* __restrict__ metric) {
  int h = blockIdx.x, t = threadIdx.x;
  __shared__ float P[64][65];
  if (t < 64) {
    int i = t;
    const float* row = pm + (size_t)(h * 64 + i) * 64;
    float mx = -1e30f;
    for (int j = 0; j <= i; ++j) mx = fmaxf(mx, row[j] * 0.125f);
    float s = 0.f;
    for (int j = 0; j <= i; ++j) { float e = expf(row[j] * 0.125f - mx); P[i][j] = e; s += e; }
    float inv = 1.f / s;
    for (int j = 0; j <= i; ++j) P[i][j] *= inv;
    for (int j = i + 1; j < 64; ++j) P[i][j] = 0.f;
  }
  __syncthreads();
  int i = t >> 2;
  int jb = (t & 3) * 16;
  for (int jj = 0; jj < 16; ++jj) {
    int j = jb + jj;
    float acc = 0.f;
    #pragma unroll
    for (int l = 0; l < 64; ++l) acc += P[i][l] * P[j][l];
    metric[(size_t)h * 4096 + i * 64 + j] = acc;
  }
}

// ---------------- bf16 MFMA GEMM: C = A @ B^T, global_load_lds staging ----------------
template <int MODE>
__launch_bounds__(256)
__global__ void gemm_xwt(const u16* __restrict__ A, const u16* __restrict__ B,
                         void* __restrict__ C0, int M, int N, int K) {
  __shared__ __align__(16) u16 As[128 * 32];
  __shared__ __align__(16) u16 Bs[128 * 32];
  int bm0 = blockIdx.y * 128, bn0 = blockIdx.x * 128;
  int t = threadIdx.x, wv = t >> 6, lane = t & 63;
  int wr = wv >> 1, wc = wv & 1;
  int l15 = lane & 15, l4 = lane >> 4;
  int rl = lane >> 2, cseg = (lane & 3) * 8;
  f32x4 acc[4][4] = {};

  for (int k0 = 0; k0 < K; k0 += 32) {
    #pragma unroll
    for (int q = 0; q < 2; ++q) {
      int rbase = (wv * 2 + q) * 16;
      gl_lds16(A + (size_t)(bm0 + rbase + rl) * K + k0 + cseg, As + rbase * 32);
      gl_lds16(B + (size_t)(bn0 + rbase + rl) * K + k0 + cseg, Bs + rbase * 32);
    }
    __syncthreads();
    bf16x8 af[4], bfm[4];
    #pragma unroll
    for (int m = 0; m < 4; ++m)
      af[m] = *reinterpret_cast<const bf16x8*>(As + (wr * 64 + m * 16 + l15) * 32 + l4 * 8);
    #pragma unroll
    for (int nn = 0; nn < 4; ++nn)
      bfm[nn] = *reinterpret_cast<const bf16x8*>(Bs + (wc * 64 + nn * 16 + l15) * 32 + l4 * 8);
    #pragma unroll
    for (int m = 0; m < 4; ++m)
      #pragma unroll
      for (int nn = 0; nn < 4; ++nn)
        acc[m][nn] = __builtin_amdgcn_mfma_f32_16x16x32_bf16(af[m], bfm[nn], acc[m][nn], 0, 0, 0);
    __syncthreads();
  }

  #pragma unroll
  for (int m = 0; m < 4; ++m) {
    int rbase = bm0 + wr * 64 + m * 16 + l4 * 4;
    #pragma unroll
    for (int nn = 0; nn < 4; ++nn) {
      int col = bn0 + wc * 64 + nn * 16 + l15;
      #pragma unroll
      for (int rr = 0; rr < 4; ++rr) {
        int row = rbase + rr;
        float v = acc[m][nn][rr];
        if (MODE == 0) {
          int bb = row >> 11, ww = row & 2047;
          int hh = col >> 6, kk = col & 63;
          ((u16*)C0)[(((size_t)(bb * NH + hh)) * SEQ + ww) * KD + kk] = f32_to_bf16(v);
        } else {
          ((float*)C0)[(size_t)row * N + col] = v;
        }
      }
    }
  }
}

// ---------------- qm = proj @ metric (per head); also emits projT [bh][d][w] ------
__launch_bounds__(256)
__global__ void qm_kernel(const u16* __restrict__ proj, const float* __restrict__ metric,
                          u16* __restrict__ qm, u16* __restrict__ projT) {
  int w0 = blockIdx.x * 32;
  int h = blockIdx.y, bb = blockIdx.z;
  __shared__ float M[64][65];
  __shared__ float Pr[32][64];
  int t = threadIdx.x;
  for (int i = t; i < 4096; i += 256) M[i >> 6][i & 63] = metric[(size_t)h * 4096 + i];
  const size_t bh = (size_t)bb * NH + h;
  const u16* pp = proj + (bh * SEQ + w0) * KD;
  for (int i = t; i < 2048; i += 256) Pr[i >> 6][i & 63] = bf16_to_f32(pp[i]);
  __syncthreads();
  int kk = t & 63, g = t >> 6;
  #pragma unroll
  for (int r8 = 0; r8 < 8; ++r8) {
    int r = r8 * 4 + g;
    float acc = 0.f;
    #pragma unroll
    for (int l = 0; l < 64; ++l) acc += Pr[r][l] * M[kk][l];  // M symmetric
    qm[(bh * SEQ + w0 + r) * KD + kk] = f32_to_bf16(acc);
  }
  // emit transposed V: projT[bh][d][w0 + ws8*8 .. +8]
  {
    int d = t & 63, ws8 = t >> 6;
    u16 tmp[8];
    #pragma unroll
    for (int i2 = 0; i2 < 8; ++i2) tmp[i2] = f32_to_bf16(Pr[ws8 * 8 + i2][d]);
    uint4 ov;
    ov.x = (u32)tmp[0] | ((u32)tmp[1] << 16);
    ov.y = (u32)tmp[2] | ((u32)tmp[3] << 16);
    ov.z = (u32)tmp[4] | ((u32)tmp[5] << 16);
    ov.w = (u32)tmp[6] | ((u32)tmp[7] << 16);
    *reinterpret_cast<uint4*>(projT + (bh * KD + d) * SEQ + w0 + ws8 * 8) = ov;
  }
}

// ---------------- causal flash attention: split-kv warps + LDS merge ----------------
// grid (32 bh, 32 pair), 256 threads = 4 warps.
// Block owns chunk pair (p, 63-p) -> uniform ~34 kv-tiles per block.
// Warps (2c+half): chunk = c? 63-p : p; half 0 takes kv tiles [0,hA), half 1 [hA,nt).
// Partials merged via LDS (O^T [64][33] f32 + m,l per chunk).
// NOTE: plain __launch_bounds__(256): the (256,4) min-waves variant forced a 64-VGPR
// cap -> ~500MB of scratch spill traffic (R5 post-mortem). ~124-160 VGPR is correct.
__launch_bounds__(256)
__global__ void attn_kernel(const u16* __restrict__ qm, const u16* __restrict__ proj,
                            const u16* __restrict__ projT, u16* __restrict__ nudged) {
  const int bh = blockIdx.x;
  const int bb = bh >> 4, h = bh & 15;
  const int p = blockIdx.y;
  const int t = threadIdx.x, wv = t >> 6, lane = t & 63;
  const int c = lane & 31, hi = lane >> 5;
  const int cidx = wv >> 1, half = wv & 1;
  const int chunk = cidx ? (63 - p) : p;
  const int q0 = chunk * 32;
  const int q_row = q0 + c;

  __shared__ float smf[2][2176];   // per chunk: O^T[64][33] + m[32]@2112 + l[32]@2144

  const size_t bho = (size_t)bh * SEQ * KD;
  const u16* kp  = proj + bho;
  const u16* qmp = qm + bho;
  const u16* vtp = projT + bho;

  const int nt = (q0 + 95) >> 6;
  const int hA = nt >> 1;
  const int s0i = half ? hA : 0;
  const int cnt = half ? (nt - hA) : hA;

  // Q fragments (B-operand), held for the whole loop
  bf16x8 qf[4];
  #pragma unroll
  for (int kc = 0; kc < 4; ++kc)
    qf[kc] = *reinterpret_cast<const bf16x8*>(qmp + (size_t)q_row * KD + kc * 16 + hi * 8);

  f32x16 o0 = {}, o1 = {};
  float mrow = -1e30f, lrow = 0.f;
  const float cl2 = 0.125f * 1.44269504088896f;   // 1/sqrt(64) * log2(e)

  // per-lane running pointers (offsets fold to immediates)
  const u16* k0p = kp + ((size_t)s0i * 64 + c) * KD;
  const u16* k1p = k0p + 32 * KD;
  const u16* v0p = vtp + (size_t)c * SEQ + s0i * 64;
  const u16* v1p = v0p + 32 * SEQ;

  bf16x8 kf0[4], kf1[4], vf0[4], vf1[4];
  #pragma unroll
  for (int kc = 0; kc < 4; ++kc) {
    kf0[kc] = *reinterpret_cast<const bf16x8*>(k0p + kc * 16 + hi * 8);
    kf1[kc] = *reinterpret_cast<const bf16x8*>(k1p + kc * 16 + hi * 8);
    vf0[kc] = *reinterpret_cast<const bf16x8*>(v0p + kc * 16 + hi * 8);
    vf1[kc] = *reinterpret_cast<const bf16x8*>(v1p + kc * 16 + hi * 8);
  }
  k0p += 64 * KD; k1p += 64 * KD; v0p += 64; v1p += 64;

  for (int i = 0; i < cnt; ++i) {
    const int j0 = (s0i + i) * 64;
    // S^T = K @ qm^T : rows=kv, cols=q (lane c owns q-col c)
    f32x16 s0 = {}, s1 = {};
    #pragma unroll
    for (int kc = 0; kc < 4; ++kc) {
      s0 = __builtin_amdgcn_mfma_f32_32x32x16_bf16(kf0[kc], qf[kc], s0, 0, 0, 0);
      s1 = __builtin_amdgcn_mfma_f32_32x32x16_bf16(kf1[kc], qf[kc], s1, 0, 0, 0);
    }
    // prefetch next K tile (hidden under softmax + PV)
    if (i + 1 < cnt) {
      #pragma unroll
      for (int kc = 0; kc < 4; ++kc) {
        kf0[kc] = *reinterpret_cast<const bf16x8*>(k0p + kc * 16 + hi * 8);
        kf1[kc] = *reinterpret_cast<const bf16x8*>(k1p + kc * 16 + hi * 8);
      }
      k0p += 64 * KD; k1p += 64 * KD;
    }
    // causal mask (uniform branch; true only on diagonal-overlapping tiles)
    if (j0 + 63 > q0) {
      #pragma unroll
      for (int r = 0; r < 16; ++r) {
        int kvl = (r & 3) + 8 * (r >> 2) + 4 * hi;
        if (j0 + kvl      > q_row) s0[r] = -1e30f;
        if (j0 + 32 + kvl > q_row) s1[r] = -1e30f;
      }
    }
    // row max: tree + one cross-half swap
    float mx[16];
    #pragma unroll
    for (int r = 0; r < 16; ++r) mx[r] = fmaxf(s0[r], s1[r]);
    #pragma unroll
    for (int st = 8; st >= 1; st >>= 1)
      #pragma unroll
      for (int r = 0; r < st; ++r) mx[r] = fmaxf(mx[r], mx[r + st]);
    float pmax = fmaxf(mx[0], __shfl_xor(mx[0], 32));
    // T13 defer-max
    if (__any(pmax - mrow > 32.f)) {
      float mn = fmaxf(mrow, pmax);
      float alpha = exp2f((mrow - mn) * cl2);
      #pragma unroll
      for (int r = 0; r < 16; ++r) { o0[r] *= alpha; o1[r] *= alpha; }
      lrow *= alpha;
      mrow = mn;
    }
    const float mc = mrow * cl2;
    float sv[16];
    #pragma unroll
    for (int r = 0; r < 16; ++r) {
      float p0 = exp2f(s0[r] * cl2 - mc); s0[r] = p0;
      float p1 = exp2f(s1[r] * cl2 - mc); s1[r] = p1;
      sv[r] = p0 + p1;
    }
    #pragma unroll
    for (int st = 8; st >= 1; st >>= 1)
      #pragma unroll
      for (int r = 0; r < st; ++r) sv[r] += sv[r + st];
    lrow += sv[0] + __shfl_xor(sv[0], 32);

    // pack P to bf16 (truncation, 1 v_perm per pair)
    u32 w[2][4][2];
    #pragma unroll
    for (int q4 = 0; q4 < 4; ++q4) {
      w[0][q4][0] = pack_trunc(s0[q4 * 4 + 0], s0[q4 * 4 + 1]);
      w[0][q4][1] = pack_trunc(s0[q4 * 4 + 2], s0[q4 * 4 + 3]);
      w[1][q4][0] = pack_trunc(s1[q4 * 4 + 0], s1[q4 * 4 + 1]);
      w[1][q4][1] = pack_trunc(s1[q4 * 4 + 2], s1[q4 * 4 + 3]);
    }
    // exchange halves -> PA frags pa[ks] = P[q=q0+c][16ks+8hi+0..7]
    bf16x8 pa[4];
    #pragma unroll
    for (int tt = 0; tt < 2; ++tt) {
      #pragma unroll
      for (int j = 0; j < 2; ++j) {
        int own = 2 * j + hi, send = 2 * j + (hi ^ 1);
        u32 ra = __shfl_xor(w[tt][send][0], 32);
        u32 rb = __shfl_xor(w[tt][send][1], 32);
        union { u32 u[4]; bf16x8 v; } pk;
        if (hi == 0) { pk.u[0] = w[tt][own][0]; pk.u[1] = w[tt][own][1]; pk.u[2] = ra; pk.u[3] = rb; }
        else         { pk.u[0] = ra; pk.u[1] = rb; pk.u[2] = w[tt][own][0]; pk.u[3] = w[tt][own][1]; }
        pa[tt * 2 + j] = pk.v;
      }
    }
    // O^T += V^T @ P^T (stats stay lane-local)
    #pragma unroll
    for (int ks = 0; ks < 4; ++ks) {
      o0 = __builtin_amdgcn_mfma_f32_32x32x16_bf16(vf0[ks], pa[ks], o0, 0, 0, 0);
      o1 = __builtin_amdgcn_mfma_f32_32x32x16_bf16(vf1[ks], pa[ks], o1, 0, 0, 0);
    }
    // prefetch next V^T tile
    if (i + 1 < cnt) {
      #pragma unroll
      for (int ks = 0; ks < 4; ++ks) {
        vf0[ks] = *reinterpret_cast<const bf16x8*>(v0p + ks * 16 + hi * 8);
        vf1[ks] = *reinterpret_cast<const bf16x8*>(v1p + ks * 16 + hi * 8);
      }
      v0p += 64; v1p += 64;
    }
  }

  // ---- merge halves: odd warp publishes partials, even warp merges + stores ----
  float* Ob = smf[cidx];
  if (half == 1) {
    #pragma unroll
    for (int r = 0; r < 16; ++r) {
      int d = (r & 3) + 8 * (r >> 2) + 4 * hi;
      Ob[d * 33 + c] = o0[r];
      Ob[(d + 32) * 33 + c] = o1[r];
    }
    if (hi == 0) { Ob[2112 + c] = mrow; Ob[2144 + c] = lrow; }
  }
  __syncthreads();
  if (half == 0) {
    float mB = Ob[2112 + c], lB = Ob[2144 + c];
    float Mx = fmaxf(mrow, mB);
    float scA = exp2f((mrow - Mx) * cl2);
    float scB = exp2f((mB - Mx) * cl2);
    float invd = 1.f / (lrow * scA + lB * scB);
    float v0[16], v1[16];
    #pragma unroll
    for (int r = 0; r < 16; ++r) {
      int d = (r & 3) + 8 * (r >> 2) + 4 * hi;
      v0[r] = (o0[r] * scA + Ob[d * 33 + c] * scB) * invd;
      v1[r] = (o1[r] * scA + Ob[(d + 32) * 33 + c] * scB) * invd;
    }
    u16* orow = nudged + ((size_t)bb * SEQ + q_row) * CDIM + h * KD;
    #pragma unroll
    for (int g = 0; g < 4; ++g) {
      int d0 = g * 8 + hi * 4;
      uint2 a, b2;
      a.x  = pack_bf16x2(v0[g * 4 + 0], v0[g * 4 + 1]);
      a.y  = pack_bf16x2(v0[g * 4 + 2], v0[g * 4 + 3]);
      b2.x = pack_bf16x2(v1[g * 4 + 0], v1[g * 4 + 1]);
      b2.y = pack_bf16x2(v1[g * 4 + 2], v1[g * 4 + 3]);
      *reinterpret_cast<uint2*>(orow + d0)      = a;
      *reinterpret_cast<uint2*>(orow + 32 + d0) = b2;
    }
  }
}

// ---------------- host launch ----------------
extern "C" void kernel_launch(void* const* d_in, const int* in_sizes, int n_in,
                              void* d_out, int out_size, void* d_ws, size_t ws_size,
                              hipStream_t stream) {
  (void)in_sizes; (void)n_in; (void)out_size; (void)ws_size;
  const float* x      = (const float*)d_in[0];
  const float* Wproj  = (const float*)d_in[1];
  const float* premet = (const float*)d_in[2];
  const float* Wmix   = (const float*)d_in[3];

  char* w = (char*)d_ws;
  u16* x_bf   = (u16*)w;  w += (size_t)MROWS * CDIM * 2;        // 8 MB
  u16* wp_bf  = (u16*)w;  w += (size_t)CDIM * CDIM * 2;         // 2 MB
  u16* wm_bf  = (u16*)w;  w += (size_t)CDIM * CDIM * 2;         // 2 MB
  float* metric = (float*)w; w += (size_t)NH * KD * KD * 4;     // 256 KB
  u16* proj_bnwk = (u16*)w; w += (size_t)BATCH * NH * SEQ * KD * 2;  // 8 MB
  u16* projT     = (u16*)w; w += (size_t)BATCH * NH * KD * SEQ * 2;  // 8 MB
  u16* qm        = (u16*)w; w += (size_t)BATCH * NH * SEQ * KD * 2;  // 8 MB
  u16* nudged    = (u16*)w; w += (size_t)MROWS * CDIM * 2;           // 8 MB

  hipLaunchKernelGGL(cvt_all, dim3(2048), dim3(256), 0, stream,
                     x, Wproj, Wmix, x_bf, wp_bf, wm_bf);
  hipLaunchKernelGGL(metric_kernel, dim3(NH), dim3(256), 0, stream, premet, metric);
  hipLaunchKernelGGL((gemm_xwt<0>), dim3(CDIM / 128, MROWS / 128), dim3(256), 0, stream,
                     x_bf, wp_bf, (void*)proj_bnwk, MROWS, CDIM, CDIM);
  hipLaunchKernelGGL(qm_kernel, dim3(SEQ / 32, NH, BATCH), dim3(256), 0, stream,
                     proj_bnwk, metric, qm, projT);
  hipLaunchKernelGGL(attn_kernel, dim3(32, 32), dim3(256), 0, stream,
                     qm, proj_bnwk, projT, nudged);
  hipLaunchKernelGGL((gemm_xwt<1>), dim3(CDIM / 128, MROWS / 128), dim3(256), 0, stream,
                     nudged, wm_bf, d_out, MROWS, CDIM, CDIM);
}

// Round 8
// 207.324 us; speedup vs baseline: 1.6217x; 1.0847x over previous
//
#include <hip/hip_runtime.h>
#include <stdint.h>
#include <stddef.h>

typedef unsigned short u16;
typedef unsigned int u32;
typedef __attribute__((ext_vector_type(8))) __bf16 bf16x8;
typedef __attribute__((ext_vector_type(4))) float f32x4;
typedef __attribute__((ext_vector_type(16))) float f32x16;

#define DEV __device__ __forceinline__

// ---- problem dims (hardcoded per reference) ----
#define BATCH 2
#define SEQ   2048
#define CDIM  1024
#define NH    16
#define KD    64
#define MROWS (BATCH * SEQ)   // 4096
#define NX (MROWS * CDIM)     // 4194304
#define NW (CDIM * CDIM)      // 1048576

DEV u16 f32_to_bf16(float f) {
  union { float f; unsigned u; } v; v.f = f;
  return (u16)((v.u + 0x7fffu + ((v.u >> 16) & 1u)) >> 16);
}
DEV float bf16_to_f32(u16 h) {
  union { unsigned u; float f; } v; v.u = ((unsigned)h) << 16;
  return v.f;
}
DEV u32 pack_bf16x2(float a, float b) {
  union { __bf16 h[2]; u32 u; } r;
  r.h[0] = (__bf16)a; r.h[1] = (__bf16)b;
  return r.u;
}
// truncation pack: low16 = hi16(a), high16 = hi16(b) -- single v_perm_b32
DEV u32 pack_trunc(float a, float b) {
  return __builtin_amdgcn_perm(__float_as_uint(b), __float_as_uint(a), 0x07060302u);
}
// raw 2^x (single v_exp_f32, no OCML wrapper)
DEV float v_exp2(float x) {
  float r; asm("v_exp_f32 %0, %1" : "=v"(r) : "v"(x)); return r;
}

// async global->LDS, 16B per lane
DEV void gl_lds16(const u16* g, u16* l) {
  __builtin_amdgcn_global_load_lds(
      (const __attribute__((address_space(1))) void*)(g),
      (__attribute__((address_space(3))) void*)(l), 16, 0, 0);
}

// ---------------- fused: f32->bf16 convert (blocks 0..2047) + metric (2048..2063) ----
// metric = (row-softmax of tril(pm)/8) @ P^T
__global__ void cvt_metric(const float* __restrict__ x, const float* __restrict__ wp,
                           const float* __restrict__ wm, const float* __restrict__ pm,
                           u16* __restrict__ xb, u16* __restrict__ wpb,
                           u16* __restrict__ wmb, float* __restrict__ metric) {
  __shared__ float P[64][65];
  int bid = blockIdx.x, t = threadIdx.x;
  if (bid < 2048) {
    int total4 = (NX + 2 * NW) >> 2;
    for (int i4 = bid * 256 + t; i4 < total4; i4 += 2048 * 256) {
      int i = i4 << 2;
      const float* src; u16* dst; int off;
      if (i < NX)           { src = x;  dst = xb;  off = i; }
      else if (i < NX + NW) { src = wp; dst = wpb; off = i - NX; }
      else                  { src = wm; dst = wmb; off = i - NX - NW; }
      float4 v = *reinterpret_cast<const float4*>(src + off);
      ushort4 o;
      o.x = f32_to_bf16(v.x); o.y = f32_to_bf16(v.y);
      o.z = f32_to_bf16(v.z); o.w = f32_to_bf16(v.w);
      *reinterpret_cast<ushort4*>(dst + off) = o;
    }
    return;
  }
  int h = bid - 2048;
  if (t < 64) {
    int i = t;
    const float* row = pm + (size_t)(h * 64 + i) * 64;
    float mx = -1e30f;
    for (int j = 0; j <= i; ++j) mx = fmaxf(mx, row[j] * 0.125f);
    float s = 0.f;
    for (int j = 0; j <= i; ++j) { float e = expf(row[j] * 0.125f - mx); P[i][j] = e; s += e; }
    float inv = 1.f / s;
    for (int j = 0; j <= i; ++j) P[i][j] *= inv;
    for (int j = i + 1; j < 64; ++j) P[i][j] = 0.f;
  }
  __syncthreads();
  int i = t >> 2;
  int jb = (t & 3) * 16;
  for (int jj = 0; jj < 16; ++jj) {
    int j = jb + jj;
    float acc = 0.f;
    #pragma unroll
    for (int l = 0; l < 64; ++l) acc += P[i][l] * P[j][l];
    metric[(size_t)h * 4096 + i * 64 + j] = acc;
  }
}

// ---------------- bf16 MFMA GEMM: C = A @ B^T, global_load_lds staging ----------------
template <int MODE>
__launch_bounds__(256)
__global__ void gemm_xwt(const u16* __restrict__ A, const u16* __restrict__ B,
                         void* __restrict__ C0, int M, int N, int K) {
  __shared__ __align__(16) u16 As[128 * 32];
  __shared__ __align__(16) u16 Bs[128 * 32];
  int bm0 = blockIdx.y * 128, bn0 = blockIdx.x * 128;
  int t = threadIdx.x, wv = t >> 6, lane = t & 63;
  int wr = wv >> 1, wc = wv & 1;
  int l15 = lane & 15, l4 = lane >> 4;
  int rl = lane >> 2, cseg = (lane & 3) * 8;
  f32x4 acc[4][4] = {};

  for (int k0 = 0; k0 < K; k0 += 32) {
    #pragma unroll
    for (int q = 0; q < 2; ++q) {
      int rbase = (wv * 2 + q) * 16;
      gl_lds16(A + (size_t)(bm0 + rbase + rl) * K + k0 + cseg, As + rbase * 32);
      gl_lds16(B + (size_t)(bn0 + rbase + rl) * K + k0 + cseg, Bs + rbase * 32);
    }
    __syncthreads();
    bf16x8 af[4], bfm[4];
    #pragma unroll
    for (int m = 0; m < 4; ++m)
      af[m] = *reinterpret_cast<const bf16x8*>(As + (wr * 64 + m * 16 + l15) * 32 + l4 * 8);
    #pragma unroll
    for (int nn = 0; nn < 4; ++nn)
      bfm[nn] = *reinterpret_cast<const bf16x8*>(Bs + (wc * 64 + nn * 16 + l15) * 32 + l4 * 8);
    #pragma unroll
    for (int m = 0; m < 4; ++m)
      #pragma unroll
      for (int nn = 0; nn < 4; ++nn)
        acc[m][nn] = __builtin_amdgcn_mfma_f32_16x16x32_bf16(af[m], bfm[nn], acc[m][nn], 0, 0, 0);
    __syncthreads();
  }

  #pragma unroll
  for (int m = 0; m < 4; ++m) {
    int rbase = bm0 + wr * 64 + m * 16 + l4 * 4;
    #pragma unroll
    for (int nn = 0; nn < 4; ++nn) {
      int col = bn0 + wc * 64 + nn * 16 + l15;
      #pragma unroll
      for (int rr = 0; rr < 4; ++rr) {
        int row = rbase + rr;
        float v = acc[m][nn][rr];
        if (MODE == 0) {
          int bb = row >> 11, ww = row & 2047;
          int hh = col >> 6, kk = col & 63;
          ((u16*)C0)[(((size_t)(bb * NH + hh)) * SEQ + ww) * KD + kk] = f32_to_bf16(v);
        } else {
          ((float*)C0)[(size_t)row * N + col] = v;
        }
      }
    }
  }
}

// ---------------- qm = proj @ metric (per head); also emits projT [bh][d][w] ------
__launch_bounds__(256)
__global__ void qm_kernel(const u16* __restrict__ proj, const float* __restrict__ metric,
                          u16* __restrict__ qm, u16* __restrict__ projT) {
  int w0 = blockIdx.x * 32;
  int h = blockIdx.y, bb = blockIdx.z;
  __shared__ float M[64][65];
  __shared__ float Pr[32][64];
  int t = threadIdx.x;
  for (int i = t; i < 4096; i += 256) M[i >> 6][i & 63] = metric[(size_t)h * 4096 + i];
  const size_t bh = (size_t)bb * NH + h;
  const u16* pp = proj + (bh * SEQ + w0) * KD;
  for (int i = t; i < 2048; i += 256) Pr[i >> 6][i & 63] = bf16_to_f32(pp[i]);
  __syncthreads();
  int kk = t & 63, g = t >> 6;
  #pragma unroll
  for (int r8 = 0; r8 < 8; ++r8) {
    int r = r8 * 4 + g;
    float acc = 0.f;
    #pragma unroll
    for (int l = 0; l < 64; ++l) acc += Pr[r][l] * M[kk][l];  // M symmetric
    qm[(bh * SEQ + w0 + r) * KD + kk] = f32_to_bf16(acc);
  }
  // emit transposed V: projT[bh][d][w0 + ws8*8 .. +8]
  {
    int d = t & 63, ws8 = t >> 6;
    u16 tmp[8];
    #pragma unroll
    for (int i2 = 0; i2 < 8; ++i2) tmp[i2] = f32_to_bf16(Pr[ws8 * 8 + i2][d]);
    uint4 ov;
    ov.x = (u32)tmp[0] | ((u32)tmp[1] << 16);
    ov.y = (u32)tmp[2] | ((u32)tmp[3] << 16);
    ov.z = (u32)tmp[4] | ((u32)tmp[5] << 16);
    ov.w = (u32)tmp[6] | ((u32)tmp[7] << 16);
    *reinterpret_cast<uint4*>(projT + (bh * KD + d) * SEQ + w0 + ws8 * 8) = ov;
  }
}

// ---------------- causal flash attention: split-kv warps + LDS merge ----------------
// grid (32 bh, 32 pair), 256 threads = 4 warps; chunk pair (p, 63-p) per block.
// MAX-FREE softmax (scores bounded, |s*cl2| << 126): p = 2^(S*cl2) directly; no
// running max, no rescale; l accumulated in 8 regs, reduced once after the loop.
// P->PA exchange: __shfl_xor(32) path (R6-verified). NOTE: v_permlane32_swap_b32
// attempt (R7) had wrong register-half semantics -> permuted P, FAILED correctness.
__launch_bounds__(256)
__global__ void attn_kernel(const u16* __restrict__ qm, const u16* __restrict__ proj,
                            const u16* __restrict__ projT, u16* __restrict__ nudged) {
  const int bh = blockIdx.x;
  const int bb = bh >> 4, h = bh & 15;
  const int p = blockIdx.y;
  const int t = threadIdx.x, wv = t >> 6, lane = t & 63;
  const int c = lane & 31, hi = lane >> 5;
  const int cidx = wv >> 1, half = wv & 1;
  const int chunk = cidx ? (63 - p) : p;
  const int q0 = chunk * 32;
  const int q_row = q0 + c;

  __shared__ float smf[2][2176];   // per chunk: O^T[64][33] + l[32]@2112

  const size_t bho = (size_t)bh * SEQ * KD;
  const u16* kp  = proj + bho;
  const u16* qmp = qm + bho;
  const u16* vtp = projT + bho;

  const int nt = (q0 + 95) >> 6;
  const int hA = nt >> 1;
  const int s0i = half ? hA : 0;
  const int cnt = half ? (nt - hA) : hA;

  // Q fragments (B-operand), held for the whole loop
  bf16x8 qf[4];
  #pragma unroll
  for (int kc = 0; kc < 4; ++kc)
    qf[kc] = *reinterpret_cast<const bf16x8*>(qmp + (size_t)q_row * KD + kc * 16 + hi * 8);

  f32x16 o0 = {}, o1 = {};
  float sv[8] = {};
  const float cl2 = 0.125f * 1.44269504088896f;   // 1/sqrt(64) * log2(e)

  // per-lane running pointers (offsets fold to immediates)
  const u16* k0p = kp + ((size_t)s0i * 64 + c) * KD;
  const u16* k1p = k0p + 32 * KD;
  const u16* v0p = vtp + (size_t)c * SEQ + s0i * 64;
  const u16* v1p = v0p + 32 * SEQ;

  bf16x8 kf0[4], kf1[4], vf0[4], vf1[4];
  #pragma unroll
  for (int kc = 0; kc < 4; ++kc) {
    kf0[kc] = *reinterpret_cast<const bf16x8*>(k0p + kc * 16 + hi * 8);
    kf1[kc] = *reinterpret_cast<const bf16x8*>(k1p + kc * 16 + hi * 8);
    vf0[kc] = *reinterpret_cast<const bf16x8*>(v0p + kc * 16 + hi * 8);
    vf1[kc] = *reinterpret_cast<const bf16x8*>(v1p + kc * 16 + hi * 8);
  }
  k0p += 64 * KD; k1p += 64 * KD; v0p += 64; v1p += 64;

  for (int i = 0; i < cnt; ++i) {
    const int j0 = (s0i + i) * 64;
    // S^T = K @ qm^T : rows=kv, cols=q (lane c owns q-col c)
    f32x16 s0 = {}, s1 = {};
    #pragma unroll
    for (int kc = 0; kc < 4; ++kc) {
      s0 = __builtin_amdgcn_mfma_f32_32x32x16_bf16(kf0[kc], qf[kc], s0, 0, 0, 0);
      s1 = __builtin_amdgcn_mfma_f32_32x32x16_bf16(kf1[kc], qf[kc], s1, 0, 0, 0);
    }
    // prefetch next K tile (hidden under softmax + PV)
    if (i + 1 < cnt) {
      #pragma unroll
      for (int kc = 0; kc < 4; ++kc) {
        kf0[kc] = *reinterpret_cast<const bf16x8*>(k0p + kc * 16 + hi * 8);
        kf1[kc] = *reinterpret_cast<const bf16x8*>(k1p + kc * 16 + hi * 8);
      }
      k0p += 64 * KD; k1p += 64 * KD;
    }
    // causal mask (uniform branch; true only on diagonal-overlapping tiles)
    if (j0 + 63 > q0) {
      #pragma unroll
      for (int r = 0; r < 16; ++r) {
        int kvl = (r & 3) + 8 * (r >> 2) + 4 * hi;
        if (j0 + kvl      > q_row) s0[r] = -1e30f;
        if (j0 + 32 + kvl > q_row) s1[r] = -1e30f;
      }
    }
    // max-free softmax: p = 2^(s*cl2); accumulate row-sum into 8 regs
    #pragma unroll
    for (int r = 0; r < 16; ++r) {
      float p0 = v_exp2(s0[r] * cl2); s0[r] = p0;
      float p1 = v_exp2(s1[r] * cl2); s1[r] = p1;
      sv[r & 7] += p0 + p1;
    }
    // pack P to bf16 (truncation) and exchange halves via shfl_xor(32)
    u32 w[2][4][2];
    #pragma unroll
    for (int q4 = 0; q4 < 4; ++q4) {
      w[0][q4][0] = pack_trunc(s0[q4 * 4 + 0], s0[q4 * 4 + 1]);
      w[0][q4][1] = pack_trunc(s0[q4 * 4 + 2], s0[q4 * 4 + 3]);
      w[1][q4][0] = pack_trunc(s1[q4 * 4 + 0], s1[q4 * 4 + 1]);
      w[1][q4][1] = pack_trunc(s1[q4 * 4 + 2], s1[q4 * 4 + 3]);
    }
    // pa[ks] = P[q=q0+c][16ks+8hi+0..7]
    bf16x8 pa[4];
    #pragma unroll
    for (int tt = 0; tt < 2; ++tt) {
      #pragma unroll
      for (int j = 0; j < 2; ++j) {
        int own = 2 * j + hi, send = 2 * j + (hi ^ 1);
        u32 ra = __shfl_xor(w[tt][send][0], 32);
        u32 rb = __shfl_xor(w[tt][send][1], 32);
        union { u32 u[4]; bf16x8 v; } pk;
        if (hi == 0) { pk.u[0] = w[tt][own][0]; pk.u[1] = w[tt][own][1]; pk.u[2] = ra; pk.u[3] = rb; }
        else         { pk.u[0] = ra; pk.u[1] = rb; pk.u[2] = w[tt][own][0]; pk.u[3] = w[tt][own][1]; }
        pa[tt * 2 + j] = pk.v;
      }
    }
    // O^T += V^T @ P^T
    #pragma unroll
    for (int ks = 0; ks < 4; ++ks) {
      o0 = __builtin_amdgcn_mfma_f32_32x32x16_bf16(vf0[ks], pa[ks], o0, 0, 0, 0);
      o1 = __builtin_amdgcn_mfma_f32_32x32x16_bf16(vf1[ks], pa[ks], o1, 0, 0, 0);
    }
    // prefetch next V^T tile
    if (i + 1 < cnt) {
      #pragma unroll
      for (int ks = 0; ks < 4; ++ks) {
        vf0[ks] = *reinterpret_cast<const bf16x8*>(v0p + ks * 16 + hi * 8);
        vf1[ks] = *reinterpret_cast<const bf16x8*>(v1p + ks * 16 + hi * 8);
      }
      v0p += 64; v1p += 64;
    }
  }

  // final row-sum: 8-reg tree + cross-half add
  float lrow;
  {
    float a0 = (sv[0] + sv[4]) + (sv[1] + sv[5]);
    float a1 = (sv[2] + sv[6]) + (sv[3] + sv[7]);
    float s = a0 + a1;
    lrow = s + __shfl_xor(s, 32);
  }

  // ---- merge halves: odd warp publishes partials, even warp merges + stores ----
  float* Ob = smf[cidx];
  if (half == 1) {
    #pragma unroll
    for (int r = 0; r < 16; ++r) {
      int d = (r & 3) + 8 * (r >> 2) + 4 * hi;
      Ob[d * 33 + c] = o0[r];
      Ob[(d + 32) * 33 + c] = o1[r];
    }
    if (hi == 0) Ob[2112 + c] = lrow;
  }
  __syncthreads();
  if (half == 0) {
    float invd = 1.f / (lrow + Ob[2112 + c]);
    float v0[16], v1[16];
    #pragma unroll
    for (int r = 0; r < 16; ++r) {
      int d = (r & 3) + 8 * (r >> 2) + 4 * hi;
      v0[r] = (o0[r] + Ob[d * 33 + c]) * invd;
      v1[r] = (o1[r] + Ob[(d + 32) * 33 + c]) * invd;
    }
    u16* orow = nudged + ((size_t)bb * SEQ + q_row) * CDIM + h * KD;
    #pragma unroll
    for (int g = 0; g < 4; ++g) {
      int d0 = g * 8 + hi * 4;
      uint2 a, b2;
      a.x  = pack_bf16x2(v0[g * 4 + 0], v0[g * 4 + 1]);
      a.y  = pack_bf16x2(v0[g * 4 + 2], v0[g * 4 + 3]);
      b2.x = pack_bf16x2(v1[g * 4 + 0], v1[g * 4 + 1]);
      b2.y = pack_bf16x2(v1[g * 4 + 2], v1[g * 4 + 3]);
      *reinterpret_cast<uint2*>(orow + d0)      = a;
      *reinterpret_cast<uint2*>(orow + 32 + d0) = b2;
    }
  }
}

// ---------------- host launch ----------------
extern "C" void kernel_launch(void* const* d_in, const int* in_sizes, int n_in,
                              void* d_out, int out_size, void* d_ws, size_t ws_size,
                              hipStream_t stream) {
  (void)in_sizes; (void)n_in; (void)out_size; (void)ws_size;
  const float* x      = (const float*)d_in[0];
  const float* Wproj  = (const float*)d_in[1];
  const float* premet = (const float*)d_in[2];
  const float* Wmix   = (const float*)d_in[3];

  char* w = (char*)d_ws;
  u16* x_bf   = (u16*)w;  w += (size_t)MROWS * CDIM * 2;        // 8 MB
  u16* wp_bf  = (u16*)w;  w += (size_t)CDIM * CDIM * 2;         // 2 MB
  u16* wm_bf  = (u16*)w;  w += (size_t)CDIM * CDIM * 2;         // 2 MB
  float* metric = (float*)w; w += (size_t)NH * KD * KD * 4;     // 256 KB
  u16* proj_bnwk = (u16*)w; w += (size_t)BATCH * NH * SEQ * KD * 2;  // 8 MB
  u16* projT     = (u16*)w; w += (size_t)BATCH * NH * KD * SEQ * 2;  // 8 MB
  u16* qm        = (u16*)w; w += (size_t)BATCH * NH * SEQ * KD * 2;  // 8 MB
  u16* nudged    = (u16*)w; w += (size_t)MROWS * CDIM * 2;           // 8 MB

  hipLaunchKernelGGL(cvt_metric, dim3(2064), dim3(256), 0, stream,
                     x, Wproj, Wmix, premet, x_bf, wp_bf, wm_bf, metric);
  hipLaunchKernelGGL((gemm_xwt<0>), dim3(CDIM / 128, MROWS / 128), dim3(256), 0, stream,
                     x_bf, wp_bf, (void*)proj_bnwk, MROWS, CDIM, CDIM);
  hipLaunchKernelGGL(qm_kernel, dim3(SEQ / 32, NH, BATCH), dim3(256), 0, stream,
                     proj_bnwk, metric, qm, projT);
  hipLaunchKernelGGL(attn_kernel, dim3(32, 32), dim3(256), 0, stream,
                     qm, proj_bnwk, projT, nudged);
  hipLaunchKernelGGL((gemm_xwt<1>), dim3(CDIM / 128, MROWS / 128), dim3(256), 0, stream,
                     nudged, wm_bf, d_out, MROWS, CDIM, CDIM);
}